// Round 6
// baseline (470.972 us; speedup 1.0000x reference)
//
#include <hip/hip_runtime.h>
#include <math.h>

#define Bb 64
#define Ss 128
#define BS 8192
#define Ww 16
#define CE 50
#define CH 100
#define EMBD 300
#define HID 256
#define WG 1024
#define XD 400
#define XDP 416
#define NT 50
#define KS 168

typedef unsigned short ushort_t;
typedef unsigned int uint_t;
using bf16x8 = __attribute__((ext_vector_type(8))) short;
using short8v = __attribute__((ext_vector_type(8))) short;
using short4v = __attribute__((ext_vector_type(4))) short;
using f32x4  = __attribute__((ext_vector_type(4))) float;
using int4v  = __attribute__((ext_vector_type(4))) int;

#define LBAR() do { asm volatile("s_waitcnt lgkmcnt(0)" ::: "memory"); __builtin_amdgcn_s_barrier(); } while(0)

__device__ __forceinline__ float fsig(float x){
  float e = __builtin_amdgcn_exp2f(-1.4426950408889634f * x);
  return __builtin_amdgcn_rcpf(1.0f + e);
}
__device__ __forceinline__ float ftanh(float x){
  float e = __builtin_amdgcn_exp2f(-2.8853900817779268f * fabsf(x));
  float r = 1.0f - 2.0f*e*__builtin_amdgcn_rcpf(1.0f + e);
  return copysignf(r, x);
}
__device__ __forceinline__ ushort_t f2bf(float f){
  uint_t u = __float_as_uint(f);
  uint_t r = (u + 0x7fffu + ((u>>16)&1u)) >> 16;
  return (ushort_t)r;
}
__device__ __forceinline__ float bf2f(ushort_t u){ return __uint_as_float(((uint_t)u)<<16); }

__device__ __forceinline__ int4v sel4(int c, int4v a, int4v b){
  int4v r;
  #pragma unroll
  for (int i=0;i<4;i++) r[i] = c ? a[i] : b[i];
  return r;
}

// ---------------- Wh f32 -> row-scaled int8, gates-on-M layout: Whq[dir][m=j*4+g][k]
__global__ __launch_bounds__(256) void k_cvt_whq(const float* __restrict__ whf, const float* __restrict__ whb,
                                                 signed char* __restrict__ q, float* __restrict__ dm){
  const int tid = threadIdx.x;
  const int lane = tid & 63, w = tid >> 6;
  const int gm = blockIdx.x*4 + w;          // 0..2047
  const int dir = gm >> 10, m = gm & 1023;
  const float* src = dir ? whb : whf;
  const float* row = src + (long)((m&3)*HID + (m>>2)) * HID;
  float4 v = *(const float4*)&row[lane*4];
  float mx = fmaxf(fmaxf(fabsf(v.x), fabsf(v.y)), fmaxf(fabsf(v.z), fabsf(v.w)));
  #pragma unroll
  for (int off=32; off; off>>=1) mx = fmaxf(mx, __shfl_xor(mx, off));
  float s = (mx > 0.f) ? (127.0f / mx) : 0.f;
  int b0 = __float2int_rn(v.x*s) & 255;
  int b1 = __float2int_rn(v.y*s) & 255;
  int b2 = __float2int_rn(v.z*s) & 255;
  int b3 = __float2int_rn(v.w*s) & 255;
  uint_t pk = (uint_t)b0 | ((uint_t)b1<<8) | ((uint_t)b2<<16) | ((uint_t)b3<<24);
  *(uint_t*)&q[(long)gm*HID + lane*4] = pk;
  if (lane == 0) dm[gm] = mx * (1.0f/16129.0f);   // 127*127
}

// ---------------- char BiLSTM v3: 8 waves, combined W[400][160] (h|x|pad), 3 tiles/wave
// + tile 24 via LDS on wave 7. Gates-on-M (m=j*4+g), seqs-on-N (32).
__global__ __launch_bounds__(512, 4) void k_char_mfma(const int* __restrict__ words, const float* __restrict__ cemb,
    const float* __restrict__ cWiF, const float* __restrict__ cWhF, const float* __restrict__ cbF, float* __restrict__ hfo,
    const float* __restrict__ cWiB, const float* __restrict__ cWhB, const float* __restrict__ cbB, float* __restrict__ hbo)
{
  const int rev = blockIdx.y;
  const float* cWi = rev ? cWiB : cWiF;
  const float* cWh = rev ? cWhB : cWhF;
  const float* cb  = rev ? cbB  : cbF;
  float* hout = rev ? hbo : hfo;
  const int n0 = blockIdx.x * 32;
  const int tid = threadIdx.x;
  const int lane = tid & 63;
  const int w = tid >> 6;
  const int lo = lane & 15, hi = lane >> 4;

  __shared__ ushort_t xh[32][KS];     // k-space: 0..99 = h, 100..149 = x, 150..167 pad
  __shared__ ushort_t wt24[16][KS];   // tile 24 (m=384..399) A rows, same k layout
  __shared__ float bias_l[400];
  __shared__ int wbuf[32][Ww];

  // ---- prologue ----
  for (int i = tid; i < 32*Ww; i += 512)
    wbuf[i>>4][i&15] = words[(n0 + (i>>4))*Ww + (i&15)];
  for (int i = tid; i < 32*KS/2; i += 512) ((uint_t*)xh)[i] = 0u;
  for (int i = tid; i < 400; i += 512) bias_l[i] = cb[(i&3)*CH + (i>>2)];
  for (int i = tid; i < 16*KS; i += 512){
    int rr = i / KS, k = i - rr*KS;
    int m = 384 + rr, j = m>>2, g = m&3;
    float v = 0.f;
    if (k < CH) v = cWh[(g*CH+j)*CH + k];
    else if (k < CH+CE) v = cWi[(g*CH+j)*CE + (k-CH)];
    wt24[rr][k] = f2bf(v);
  }

  // combined A-frags in registers: wave w owns tiles w*3 .. w*3+2 (0..23)
  bf16x8 wc[3][5];
  #pragma unroll
  for (int ti=0; ti<3; ++ti){
    int m = (w*3+ti)*16 + lo;
    int j = m>>2, g = m&3;
    const float* whrow = cWh + (g*CH+j)*CH;
    const float* wirow = cWi + (g*CH+j)*CE;
    #pragma unroll
    for (int kk=0; kk<5; ++kk){
      bf16x8 v;
      #pragma unroll
      for (int e=0;e<8;++e){
        int k = kk*32 + hi*8 + e;
        float f = 0.f;
        if (k < CH) f = whrow[k];
        else if (k < CH+CE) f = wirow[k-CH];
        v[e] = (short)f2bf(f);
      }
      wc[ti][kk] = v;
    }
  }

  float cst[3][2], hreg[3][2], cst4[2], hreg4[2];
  #pragma unroll
  for (int ti=0; ti<3; ++ti){ cst[ti][0]=0.f; cst[ti][1]=0.f; hreg[ti][0]=0.f; hreg[ti][1]=0.f; }
  cst4[0]=0.f; cst4[1]=0.f; hreg4[0]=0.f; hreg4[1]=0.f;

  // x staging: thread -> seq ps, elems e0..e0+3
  const int ps = tid >> 4;
  const int e0 = (tid & 15) * 4;
  float xp[4];

  __syncthreads();                    // prologue LDS ready

  {  // prefetch x_0
    int tt = rev ? (Ww-1) : 0;
    int wd = wbuf[ps][tt];
    #pragma unroll
    for (int q=0;q<4;++q){ int e = e0+q; xp[q] = (e < CE) ? cemb[wd*CE + e] : 0.f; }
  }

  #pragma unroll 1
  for (int t=0; t<Ww; ++t){
    LBAR();                           // bar A: everyone done reading xh for step t-1
    if (t){                           // write h_{t-1} into xh k 0..99
      #pragma unroll
      for (int ti=0; ti<3; ++ti){
        int j = (w*3+ti)*4 + hi;
        #pragma unroll
        for (int nt=0; nt<2; ++nt)
          xh[nt*16+lo][j] = f2bf(hreg[ti][nt]);
      }
      if (w == 7){
        #pragma unroll
        for (int nt=0; nt<2; ++nt)
          xh[nt*16+lo][96+hi] = f2bf(hreg4[nt]);
      }
    }
    // write x_t at k 100..149
    if (e0 < 48){
      short4v pv;
      #pragma unroll
      for (int q=0;q<4;++q) pv[q] = (short)f2bf(xp[q]);
      *(short4v*)&xh[ps][CH + e0] = pv;
    } else if (e0 == 48){
      xh[ps][CH+48] = f2bf(xp[0]);
      xh[ps][CH+49] = f2bf(xp[1]);
    }
    if (t+1 < Ww){                    // prefetch x_{t+1}
      int tt2 = rev ? (Ww-2-t) : (t+1);
      int wd = wbuf[ps][tt2];
      #pragma unroll
      for (int q=0;q<4;++q){ int e = e0+q; xp[q] = (e < CE) ? cemb[wd*CE + e] : 0.f; }
    }
    LBAR();                           // bar B: xh (x_t, h_{t-1}) visible

    #pragma unroll
    for (int nt=0; nt<2; ++nt){
      int s = nt*16 + lo;
      bf16x8 bfr[5];
      #pragma unroll
      for (int kk=0; kk<5; ++kk)
        bfr[kk] = *((const bf16x8*)&xh[s][kk*32 + hi*8]);
      #pragma unroll
      for (int ti=0; ti<3; ++ti){
        f32x4 acc = *((const f32x4*)&bias_l[(w*3+ti)*16 + hi*4]);
        #pragma unroll
        for (int kk=0; kk<5; ++kk)
          acc = __builtin_amdgcn_mfma_f32_16x16x32_bf16(wc[ti][kk], bfr[kk], acc, 0,0,0);
        float iv = fsig(acc[0]), fv = fsig(acc[1]);
        float gv = ftanh(acc[2]), ov = fsig(acc[3]);
        float cn = fmaf(fv, cst[ti][nt], iv*gv);
        cst[ti][nt] = cn;
        hreg[ti][nt] = ov * ftanh(cn);
      }
      if (w == 7){                    // tile 24 from LDS A-frags
        f32x4 acc = *((const f32x4*)&bias_l[384 + hi*4]);
        #pragma unroll
        for (int kk=0; kk<5; ++kk){
          bf16x8 at = *((const bf16x8*)&wt24[lo][kk*32 + hi*8]);
          acc = __builtin_amdgcn_mfma_f32_16x16x32_bf16(at, bfr[kk], acc, 0,0,0);
        }
        float iv = fsig(acc[0]), fv = fsig(acc[1]);
        float gv = ftanh(acc[2]), ov = fsig(acc[3]);
        float cn = fmaf(fv, cst4[nt], iv*gv);
        cst4[nt] = cn;
        hreg4[nt] = ov * ftanh(cn);
      }
    }
  }

  // final h -> hout
  #pragma unroll
  for (int ti=0; ti<3; ++ti){
    int j = (w*3+ti)*4 + hi;
    #pragma unroll
    for (int nt=0; nt<2; ++nt)
      hout[(n0 + nt*16 + lo)*CH + j] = hreg[ti][nt];
  }
  if (w == 7){
    #pragma unroll
    for (int nt=0; nt<2; ++nt)
      hout[(n0 + nt*16 + lo)*CH + 96 + hi] = hreg4[nt];
  }
}

// ---------------- xbf = [word_emb gather | hf+hb | 0-pad], bf16 [8192][416]
__global__ void k_build_x(const int* __restrict__ sent, const float* __restrict__ wemb,
                          const float* __restrict__ hf, const float* __restrict__ hb,
                          ushort_t* __restrict__ xbf){
  long i = (long)blockIdx.x*256 + threadIdx.x;
  if (i >= (long)BS*XDP) return;
  int n = (int)(i / XDP), e = (int)(i - (long)n*XDP);
  float v = 0.f;
  if (e < EMBD) v = wemb[(long)sent[n]*EMBD + e];
  else if (e < XD) { int jj = e-EMBD; v = hf[n*CH+jj] + hb[n*CH+jj]; }
  xbf[i] = f2bf(v);
}

// ---------------- Wi f32 -> bf16 padded: wiP[dir][1024][416]
__global__ void k_cvt_wi(const float* __restrict__ wiF, const float* __restrict__ wiB,
                         ushort_t* __restrict__ wiP){
  int i = blockIdx.x*256 + threadIdx.x;
  if (i >= 2*WG*XDP) return;
  int dir = i >= WG*XDP;
  int ii = dir ? i - WG*XDP : i;
  int n = ii / XDP, k = ii - n*XDP;
  const float* src = dir ? wiB : wiF;
  wiP[i] = (k < XD) ? f2bf(src[n*XD + k]) : (ushort_t)0;
}

// ---------------- word input-gate GEMM via bf16 MFMA; writes P layout directly.
// P[dir][t][sb][sl][m'=j*4+g]
__global__ __launch_bounds__(256) void k_gemm_mfma(const ushort_t* __restrict__ xbf, const int* __restrict__ lengths,
    const ushort_t* __restrict__ wiP, const float* __restrict__ wbF, const float* __restrict__ wbB,
    ushort_t* __restrict__ P)
{
  const int rev = blockIdx.z;
  const int b = blockIdx.x;
  const int n0 = blockIdx.y * 128;
  const float* bias = rev ? wbB : wbF;
  const int m0 = b*Ss;
  const int L = lengths[b];

  __shared__ ushort_t As[128*32];
  __shared__ ushort_t Bs[128*32];
  __shared__ float bl[128];

  const int tid = threadIdx.x;
  const int lane = tid & 63, w = tid >> 6;
  const int lo = lane & 15, hi = lane >> 4;
  const int wm0 = (w>>1)*64, wn0 = (w&1)*64;

  if (tid < 128) bl[tid] = bias[n0 + tid];

  long abase[2], bbase[2];
  #pragma unroll
  for (int u=0; u<2; ++u){
    int cid = u*256 + tid;
    int r = cid >> 2, kc = (cid & 3)*8;
    int srow;
    if (!rev) srow = m0 + r;
    else { int rr = L-1-r; srow = m0 + (rr < 0 ? 0 : rr); }
    abase[u] = (long)srow*XDP + kc;
    bbase[u] = ((long)rev*WG + n0 + r)*XDP + kc;
  }

  f32x4 acc[4][4];
  #pragma unroll
  for (int i=0;i<4;i++)
    #pragma unroll
    for (int q=0;q<4;q++){ acc[i][q][0]=0.f; acc[i][q][1]=0.f; acc[i][q][2]=0.f; acc[i][q][3]=0.f; }

  bf16x8 avn[2], bvn[2];
  #pragma unroll
  for (int u=0; u<2; ++u){
    avn[u] = *(const bf16x8*)&xbf[abase[u]];
    bvn[u] = *(const bf16x8*)&wiP[bbase[u]];
  }

  #pragma unroll 1
  for (int kt=0; kt<13; ++kt){
    bf16x8 av[2], bv[2];
    #pragma unroll
    for (int u=0; u<2; ++u){ av[u]=avn[u]; bv[u]=bvn[u]; }
    if (kt < 12){
      int k0 = (kt+1)*32;
      #pragma unroll
      for (int u=0; u<2; ++u){
        avn[u] = *(const bf16x8*)&xbf[abase[u] + k0];
        bvn[u] = *(const bf16x8*)&wiP[bbase[u] + k0];
      }
    }
    LBAR();   // all frag reads of previous tile done
    #pragma unroll
    for (int u=0; u<2; ++u){
      *(bf16x8*)&As[(u*256 + tid)*8] = av[u];
      *(bf16x8*)&Bs[(u*256 + tid)*8] = bv[u];
    }
    LBAR();   // writes visible
    bf16x8 af[4], bfr[4];
    #pragma unroll
    for (int mt=0; mt<4; ++mt) af[mt] = *(const bf16x8*)&As[(wm0 + mt*16 + lo)*32 + hi*8];
    #pragma unroll
    for (int nt=0; nt<4; ++nt) bfr[nt] = *(const bf16x8*)&Bs[(wn0 + nt*16 + lo)*32 + hi*8];
    #pragma unroll
    for (int mt=0; mt<4; ++mt)
      #pragma unroll
      for (int nt=0; nt<4; ++nt)
        acc[mt][nt] = __builtin_amdgcn_mfma_f32_16x16x32_bf16(af[mt], bfr[nt], acc[mt][nt], 0,0,0);
  }

  LBAR();
  #pragma unroll
  for (int nt=0; nt<4; ++nt){
    int n = n0 + wn0 + nt*16 + lo;            // gate-major col = g*256 + j
    float bn = bl[wn0 + nt*16 + lo];
    int mp = (n & 255)*4 + (n >> 8);          // m' = j*4 + g
    #pragma unroll
    for (int mt=0; mt<4; ++mt){
      #pragma unroll
      for (int r=0; r<4; ++r){
        int t = wm0 + mt*16 + hi*4 + r;       // 0..127
        long pidx = ((((long)rev*Ss + t)*16 + (b>>2))*4 + (b&3))*1024 + mp;
        P[pidx] = f2bf(acc[mt][nt][r] + bn);
      }
    }
  }
}

// ---------------- word LSTM recurrence via int8 MFMA K=64; Wh resident in registers.
__global__ __launch_bounds__(512, 2) void k_word_i8(
    const signed char* __restrict__ whq, const float* __restrict__ dmg,
    const ushort_t* __restrict__ P, float* __restrict__ hfw, float* __restrict__ hrw)
{
  const int dir = blockIdx.y, sb = blockIdx.x;
  const int tid = threadIdx.x, lane = tid & 63, w = tid >> 6;
  float* hout = dir ? hrw : hfw;

  __shared__ signed char hq[2][4][320];      // stride 320 -> 2-way bank aliasing (free)
  if (tid < 320) ((int*)hq)[tid] = 0;        // zero hq[0]

  const int hi = lane >> 4;
  const int lo = lane & 15;
  const int sq = lo & 3;
  const int g2 = lo >> 2;

  int4v wfr[8][4];
  #pragma unroll
  for (int ti=0; ti<8; ++ti){
    int mA = (w*8+ti)*16 + lo;
    #pragma unroll
    for (int kf=0; kf<4; ++kf)
      wfr[ti][kf] = *(const int4v*)&whq[(dir*1024 + mA)*HID + kf*64 + hi*16];
  }
  f32x4 dmq[2];
  #pragma unroll
  for (int u=0; u<2; ++u)
    dmq[u] = *(const f32x4*)&dmg[dir*1024 + (w*8 + g2*2+u)*16 + hi*4];

  float cst[2] = {0.f, 0.f};

  const ushort_t* Pd = P + (long)dir*8388608 + (sb*4 + sq)*1024;
  const ushort_t* gp0 = Pd + (w*8 + g2*2+0)*16 + hi*4;
  const ushort_t* gp1 = Pd + (w*8 + g2*2+1)*16 + hi*4;

  short4v gA[2], gB[2], gC[2];
  gA[0] = *(const short4v*)gp0;           gA[1] = *(const short4v*)gp1;
  gB[0] = *(const short4v*)(gp0 + 65536); gB[1] = *(const short4v*)(gp1 + 65536);

  const int j0 = (w*8 + g2*2)*4 + hi;     // j for u=0; u=1 is j0+4
  const long hob = (long)(sb*4 + sq)*Ss*HID;

  int p = 0;
  __syncthreads();

  #pragma unroll 1
  for (int t=0; t<Ss; ++t){
    int t2 = (t+2 < Ss) ? (t+2) : t;
    gC[0] = *(const short4v*)(gp0 + t2*65536);
    gC[1] = *(const short4v*)(gp1 + t2*65536);

    LBAR();   // h_{t-1} writes visible; global prefetch stays in flight

    int4v bfr[4];
    #pragma unroll
    for (int kf=0; kf<4; ++kf)
      bfr[kf] = *(const int4v*)&hq[p][sq][kf*64 + hi*16];

    __builtin_amdgcn_s_setprio(1);
    int4v acc[8];
    #pragma unroll
    for (int ti=0; ti<8; ++ti){
      int4v a = {0,0,0,0};
      #pragma unroll
      for (int kf=0; kf<4; ++kf)
        a = __builtin_amdgcn_mfma_i32_16x16x64_i8(wfr[ti][kf], bfr[kf], a, 0,0,0);
      acc[ti] = a;
    }
    __builtin_amdgcn_s_setprio(0);

    #pragma unroll
    for (int u=0; u<2; ++u){
      int4v x0 = sel4(g2 & 1, acc[2+u], acc[0+u]);
      int4v x1 = sel4(g2 & 1, acc[6+u], acc[4+u]);
      int4v aS = sel4(g2 & 2, x1, x0);
      float g0v = fmaf((float)aS[0], dmq[u][0], bf2f((ushort_t)gA[u][0]));
      float g1v = fmaf((float)aS[1], dmq[u][1], bf2f((ushort_t)gA[u][1]));
      float g2v = fmaf((float)aS[2], dmq[u][2], bf2f((ushort_t)gA[u][2]));
      float g3v = fmaf((float)aS[3], dmq[u][3], bf2f((ushort_t)gA[u][3]));
      float iv = fsig(g0v), fv = fsig(g1v), gg = ftanh(g2v), ov = fsig(g3v);
      float cn = fmaf(fv, cst[u], iv*gg);
      cst[u] = cn;
      float hn = ov * ftanh(cn);
      int j = j0 + u*4;
      hout[hob + (long)t*HID + j] = hn;
      hq[1-p][sq][j] = (signed char)__float2int_rn(hn * 127.0f);
    }

    gA[0]=gB[0]; gA[1]=gB[1]; gB[0]=gC[0]; gB[1]=gC[1];
    p ^= 1;
  }
}

// ---------------- emissions: emit = concat(h_fwd, h_bwd)*valid @ We^T + be
__global__ __launch_bounds__(128) void k_emit(const float* __restrict__ hfw, const float* __restrict__ hrw,
    const int* __restrict__ lengths, const float* __restrict__ We, const float* __restrict__ be,
    float* __restrict__ emit)
{
  __shared__ float Wl[NT*516];
  const int b = blockIdx.x, tg = blockIdx.y;
  const int tid = threadIdx.x;
  for (int i = tid; i < NT*512; i += 128)
    Wl[(i>>9)*516 + (i&511)] = We[i];
  __syncthreads();
  const int L = lengths[b];
  const int j = tid & 63;
  const int th = tid >> 6;
  float bej = (j<NT) ? be[j] : 0.f;
  for (int ttq=0; ttq<8; ttq++){
    int t = tg*16 + th*8 + ttq;
    int n = b*Ss + t;
    float acc = bej;
    if (j < NT && t < L){
      const float* hf_ = hfw + (long)n*HID;
      const float* hb_ = hrw + (long)(b*Ss + (L-1-t))*HID;
      const float* wr = Wl + j*516;
      for (int k=0;k<HID;k+=4){
        float4 hv = *(const float4*)(hf_+k);
        float4 wv = *(const float4*)(wr+k);
        acc += hv.x*wv.x + hv.y*wv.y + hv.z*wv.z + hv.w*wv.w;
      }
      for (int k=0;k<HID;k+=4){
        float4 hv = *(const float4*)(hb_+k);
        float4 wv = *(const float4*)(wr+256+k);
        acc += hv.x*wv.x + hv.y*wv.y + hv.z*wv.z + hv.w*wv.w;
      }
    }
    if (j < NT) emit[(long)n*NT + j] = acc;
  }
}

// ---------------- CRF: gold score + exp-domain forward algorithm; out = pred - gold
__global__ __launch_bounds__(64) void k_crf(const float* __restrict__ emit, const int* __restrict__ tags,
    const int* __restrict__ lengths, const float* __restrict__ trans, float* __restrict__ out)
{
  const int b = blockIdx.x;
  const int tid = threadIdx.x;
  __shared__ float Tl[NT*NT];
  __shared__ float A[NT];
  __shared__ float red[64];
  for (int i=tid;i<NT*NT;i+=64) Tl[i] = trans[i];
  __syncthreads();
  const int L = lengths[b];

  float gp = 0.f;
  for (int t=tid; t<L; t+=64){
    int tg = tags[b*Ss+t];
    gp += emit[(long)(b*Ss+t)*NT + tg];
    if (t>=1) gp += Tl[tags[b*Ss+t-1]*NT + tg];
  }
  red[tid] = gp; __syncthreads();
  for (int off=32; off; off>>=1){ if (tid<off) red[tid]+=red[tid+off]; __syncthreads(); }
  float gold = red[0];

  const int j = tid;
  float Ereg[NT];
  if (j < NT){
    #pragma unroll
    for (int i=0;i<NT;i++) Ereg[i] = __expf(Tl[i*NT + j]);
  }
  float a0 = (j<NT) ? emit[(long)(b*Ss)*NT + j] : -1e30f;
  float m = a0;
  #pragma unroll
  for (int off=1; off<64; off<<=1) m = fmaxf(m, __shfl_xor(m, off));
  float logZ = m;
  if (j<NT) A[j] = __expf(a0 - m);
  __syncthreads();

  for (int t=1;t<L;t++){
    float v = 0.f;
    if (j<NT){
      #pragma unroll
      for (int i=0;i<NT;i++) v = fmaf(A[i], Ereg[i], v);
      v *= __expf(emit[(long)(b*Ss+t)*NT + j]);
    }
    float mm = (j<NT) ? v : 0.f;
    #pragma unroll
    for (int off=1; off<64; off<<=1) mm = fmaxf(mm, __shfl_xor(mm, off));
    logZ += __logf(mm);
    float vn = v / mm;
    __syncthreads();
    if (j<NT) A[j] = vn;
    __syncthreads();
  }
  float s = (j<NT) ? A[j] : 0.f;
  #pragma unroll
  for (int off=1; off<64; off<<=1) s += __shfl_xor(s, off);
  float pred = logZ + __logf(s);
  if (tid==0) out[b] = pred - gold;
}

extern "C" void kernel_launch(void* const* d_in, const int* in_sizes, int n_in,
                              void* d_out, int out_size, void* d_ws, size_t ws_size,
                              hipStream_t stream){
  const int*   sentences = (const int*)d_in[0];
  const int*   lengths   = (const int*)d_in[1];
  const int*   words     = (const int*)d_in[2];
  const int*   tags      = (const int*)d_in[3];
  const float* char_emb  = (const float*)d_in[4];
  const float* cWi_f = (const float*)d_in[5];
  const float* cWh_f = (const float*)d_in[6];
  const float* cb_f  = (const float*)d_in[7];
  const float* cWi_b = (const float*)d_in[8];
  const float* cWh_b = (const float*)d_in[9];
  const float* cb_b  = (const float*)d_in[10];
  const float* word_emb = (const float*)d_in[11];
  const float* wWi_f = (const float*)d_in[12];
  const float* wWh_f = (const float*)d_in[13];
  const float* wb_f  = (const float*)d_in[14];
  const float* wWi_b = (const float*)d_in[15];
  const float* wWh_b = (const float*)d_in[16];
  const float* wb_b  = (const float*)d_in[17];
  const float* We   = (const float*)d_in[18];
  const float* be   = (const float*)d_in[19];
  const float* trans= (const float*)d_in[20];
  float* out = (float*)d_out;

  float* ws = (float*)d_ws;
  float* hf   = ws;                               // 819200 f32
  float* hb   = hf  + 819200;                     // 819200 f32
  float* hfw  = hb  + 819200;                     // 2097152 f32
  float* hrw  = hfw + 2097152;                    // 2097152 f32
  float* emit = hrw + 2097152;                    // 409600 f32
  float* dm   = emit + 409600;                    // 2048 f32
  ushort_t* xbf = (ushort_t*)(dm + 2048);         // 8192*416 bf16
  ushort_t* wiP = xbf + 3407872;                  // 2*1024*416 bf16
  ushort_t* P   = wiP + 851968;                   // 16777216 bf16
  signed char* whq = (signed char*)(P + 16777216);// 524288 i8

  k_cvt_whq<<<dim3(512), 256, 0, stream>>>(wWh_f, wWh_b, whq, dm);
  k_cvt_wi<<<dim3(3333), 256, 0, stream>>>(wWi_f, wWi_b, wiP);
  k_char_mfma<<<dim3(256,2), 512, 0, stream>>>(words, char_emb,
      cWi_f, cWh_f, cb_f, hf,
      cWi_b, cWh_b, cb_b, hb);
  k_build_x<<<dim3(13312), 256, 0, stream>>>(sentences, word_emb, hf, hb, xbf);
  k_gemm_mfma<<<dim3(64,8,2), 256, 0, stream>>>(xbf, lengths, wiP, wb_f, wb_b, P);
  k_word_i8<<<dim3(16,2), 512, 0, stream>>>(whq, dm, P, hfw, hrw);
  k_emit<<<dim3(64,8), 128, 0, stream>>>(hfw, hrw, lengths, We, be, emit);
  k_crf<<<dim3(64), 64, 0, stream>>>(emit, tags, lengths, trans, out);
}

// Round 7
// 403.468 us; speedup vs baseline: 1.1673x; 1.1673x over previous
//
#include <hip/hip_runtime.h>
#include <math.h>

#define Bb 64
#define Ss 128
#define BS 8192
#define Ww 16
#define CE 50
#define CH 100
#define EMBD 300
#define HID 256
#define WG 1024
#define XD 400
#define XDP 416
#define NT 50
#define KS 168

typedef unsigned short ushort_t;
typedef unsigned int uint_t;
using bf16x8 = __attribute__((ext_vector_type(8))) short;
using short8v = __attribute__((ext_vector_type(8))) short;
using short4v = __attribute__((ext_vector_type(4))) short;
using f32x4  = __attribute__((ext_vector_type(4))) float;
using int4v  = __attribute__((ext_vector_type(4))) int;

#define LBAR() do { asm volatile("s_waitcnt lgkmcnt(0)" ::: "memory"); __builtin_amdgcn_s_barrier(); } while(0)

__device__ __forceinline__ float fsig(float x){
  float e = __builtin_amdgcn_exp2f(-1.4426950408889634f * x);
  return __builtin_amdgcn_rcpf(1.0f + e);
}
__device__ __forceinline__ float ftanh(float x){
  float e = __builtin_amdgcn_exp2f(-2.8853900817779268f * fabsf(x));
  float r = 1.0f - 2.0f*e*__builtin_amdgcn_rcpf(1.0f + e);
  return copysignf(r, x);
}
__device__ __forceinline__ ushort_t f2bf(float f){
  uint_t u = __float_as_uint(f);
  uint_t r = (u + 0x7fffu + ((u>>16)&1u)) >> 16;
  return (ushort_t)r;
}
__device__ __forceinline__ float bf2f(ushort_t u){ return __uint_as_float(((uint_t)u)<<16); }

__device__ __forceinline__ int4v sel4(int c, int4v a, int4v b){
  int4v r;
  #pragma unroll
  for (int i=0;i<4;i++) r[i] = c ? a[i] : b[i];
  return r;
}

// ---------------- Wh f32 -> row-scaled int8, gates-on-M layout: Whq[dir][m=j*4+g][k]
__global__ __launch_bounds__(256) void k_cvt_whq(const float* __restrict__ whf, const float* __restrict__ whb,
                                                 signed char* __restrict__ q, float* __restrict__ dm){
  const int tid = threadIdx.x;
  const int lane = tid & 63, w = tid >> 6;
  const int gm = blockIdx.x*4 + w;          // 0..2047
  const int dir = gm >> 10, m = gm & 1023;
  const float* src = dir ? whb : whf;
  const float* row = src + (long)((m&3)*HID + (m>>2)) * HID;
  float4 v = *(const float4*)&row[lane*4];
  float mx = fmaxf(fmaxf(fabsf(v.x), fabsf(v.y)), fmaxf(fabsf(v.z), fabsf(v.w)));
  #pragma unroll
  for (int off=32; off; off>>=1) mx = fmaxf(mx, __shfl_xor(mx, off));
  float s = (mx > 0.f) ? (127.0f / mx) : 0.f;
  int b0 = __float2int_rn(v.x*s) & 255;
  int b1 = __float2int_rn(v.y*s) & 255;
  int b2 = __float2int_rn(v.z*s) & 255;
  int b3 = __float2int_rn(v.w*s) & 255;
  uint_t pk = (uint_t)b0 | ((uint_t)b1<<8) | ((uint_t)b2<<16) | ((uint_t)b3<<24);
  *(uint_t*)&q[(long)gm*HID + lane*4] = pk;
  if (lane == 0) dm[gm] = mx * (1.0f/16129.0f);   // 127*127
}

// ---------------- char BiLSTM v3: 8 waves, combined W[400][160] (h|x|pad), 3 tiles/wave
// + tile 24 via LDS on wave 7. Gates-on-M (m=j*4+g), seqs-on-N (32).
// launch_bounds(512,2): cap 256 regs/wave -> wc stays register-resident (r6: (512,4)
// split the unified file 64/64 and spilled 307MB/dispatch to scratch).
__global__ __launch_bounds__(512, 2) void k_char_mfma(const int* __restrict__ words, const float* __restrict__ cemb,
    const float* __restrict__ cWiF, const float* __restrict__ cWhF, const float* __restrict__ cbF, float* __restrict__ hfo,
    const float* __restrict__ cWiB, const float* __restrict__ cWhB, const float* __restrict__ cbB, float* __restrict__ hbo)
{
  const int rev = blockIdx.y;
  const float* cWi = rev ? cWiB : cWiF;
  const float* cWh = rev ? cWhB : cWhF;
  const float* cb  = rev ? cbB  : cbF;
  float* hout = rev ? hbo : hfo;
  const int n0 = blockIdx.x * 32;
  const int tid = threadIdx.x;
  const int lane = tid & 63;
  const int w = tid >> 6;
  const int lo = lane & 15, hi = lane >> 4;

  __shared__ ushort_t xh[32][KS];     // k-space: 0..99 = h, 100..149 = x, 150..167 pad
  __shared__ ushort_t wt24[16][KS];   // tile 24 (m=384..399) A rows, same k layout
  __shared__ float bias_l[400];
  __shared__ int wbuf[32][Ww];

  // ---- prologue ----
  for (int i = tid; i < 32*Ww; i += 512)
    wbuf[i>>4][i&15] = words[(n0 + (i>>4))*Ww + (i&15)];
  for (int i = tid; i < 32*KS/2; i += 512) ((uint_t*)xh)[i] = 0u;
  for (int i = tid; i < 400; i += 512) bias_l[i] = cb[(i&3)*CH + (i>>2)];
  for (int i = tid; i < 16*KS; i += 512){
    int rr = i / KS, k = i - rr*KS;
    int m = 384 + rr, j = m>>2, g = m&3;
    float v = 0.f;
    if (k < CH) v = cWh[(g*CH+j)*CH + k];
    else if (k < CH+CE) v = cWi[(g*CH+j)*CE + (k-CH)];
    wt24[rr][k] = f2bf(v);
  }

  // combined A-frags in registers: wave w owns tiles w*3 .. w*3+2 (0..23)
  bf16x8 wc[3][5];
  #pragma unroll
  for (int ti=0; ti<3; ++ti){
    int m = (w*3+ti)*16 + lo;
    int j = m>>2, g = m&3;
    const float* whrow = cWh + (g*CH+j)*CH;
    const float* wirow = cWi + (g*CH+j)*CE;
    #pragma unroll
    for (int kk=0; kk<5; ++kk){
      bf16x8 v;
      #pragma unroll
      for (int e=0;e<8;++e){
        int k = kk*32 + hi*8 + e;
        float f = 0.f;
        if (k < CH) f = whrow[k];
        else if (k < CH+CE) f = wirow[k-CH];
        v[e] = (short)f2bf(f);
      }
      wc[ti][kk] = v;
    }
  }

  float cst[3][2], hreg[3][2], cst4[2], hreg4[2];
  #pragma unroll
  for (int ti=0; ti<3; ++ti){ cst[ti][0]=0.f; cst[ti][1]=0.f; hreg[ti][0]=0.f; hreg[ti][1]=0.f; }
  cst4[0]=0.f; cst4[1]=0.f; hreg4[0]=0.f; hreg4[1]=0.f;

  // x staging: thread -> seq ps, elems e0..e0+3
  const int ps = tid >> 4;
  const int e0 = (tid & 15) * 4;
  float xp[4];

  __syncthreads();                    // prologue LDS ready

  {  // prefetch x_0
    int tt = rev ? (Ww-1) : 0;
    int wd = wbuf[ps][tt];
    #pragma unroll
    for (int q=0;q<4;++q){ int e = e0+q; xp[q] = (e < CE) ? cemb[wd*CE + e] : 0.f; }
  }

  #pragma unroll 1
  for (int t=0; t<Ww; ++t){
    LBAR();                           // bar A: everyone done reading xh for step t-1
    if (t){                           // write h_{t-1} into xh k 0..99
      #pragma unroll
      for (int ti=0; ti<3; ++ti){
        int j = (w*3+ti)*4 + hi;
        #pragma unroll
        for (int nt=0; nt<2; ++nt)
          xh[nt*16+lo][j] = f2bf(hreg[ti][nt]);
      }
      if (w == 7){
        #pragma unroll
        for (int nt=0; nt<2; ++nt)
          xh[nt*16+lo][96+hi] = f2bf(hreg4[nt]);
      }
    }
    // write x_t at k 100..149
    if (e0 < 48){
      short4v pv;
      #pragma unroll
      for (int q=0;q<4;++q) pv[q] = (short)f2bf(xp[q]);
      *(short4v*)&xh[ps][CH + e0] = pv;
    } else if (e0 == 48){
      xh[ps][CH+48] = f2bf(xp[0]);
      xh[ps][CH+49] = f2bf(xp[1]);
    }
    if (t+1 < Ww){                    // prefetch x_{t+1}
      int tt2 = rev ? (Ww-2-t) : (t+1);
      int wd = wbuf[ps][tt2];
      #pragma unroll
      for (int q=0;q<4;++q){ int e = e0+q; xp[q] = (e < CE) ? cemb[wd*CE + e] : 0.f; }
    }
    LBAR();                           // bar B: xh (x_t, h_{t-1}) visible

    #pragma unroll
    for (int nt=0; nt<2; ++nt){
      int s = nt*16 + lo;
      bf16x8 bfr[5];
      #pragma unroll
      for (int kk=0; kk<5; ++kk)
        bfr[kk] = *((const bf16x8*)&xh[s][kk*32 + hi*8]);
      #pragma unroll
      for (int ti=0; ti<3; ++ti){
        f32x4 acc = *((const f32x4*)&bias_l[(w*3+ti)*16 + hi*4]);
        #pragma unroll
        for (int kk=0; kk<5; ++kk)
          acc = __builtin_amdgcn_mfma_f32_16x16x32_bf16(wc[ti][kk], bfr[kk], acc, 0,0,0);
        float iv = fsig(acc[0]), fv = fsig(acc[1]);
        float gv = ftanh(acc[2]), ov = fsig(acc[3]);
        float cn = fmaf(fv, cst[ti][nt], iv*gv);
        cst[ti][nt] = cn;
        hreg[ti][nt] = ov * ftanh(cn);
      }
      if (w == 7){                    // tile 24 from LDS A-frags
        f32x4 acc = *((const f32x4*)&bias_l[384 + hi*4]);
        #pragma unroll
        for (int kk=0; kk<5; ++kk){
          bf16x8 at = *((const bf16x8*)&wt24[lo][kk*32 + hi*8]);
          acc = __builtin_amdgcn_mfma_f32_16x16x32_bf16(at, bfr[kk], acc, 0,0,0);
        }
        float iv = fsig(acc[0]), fv = fsig(acc[1]);
        float gv = ftanh(acc[2]), ov = fsig(acc[3]);
        float cn = fmaf(fv, cst4[nt], iv*gv);
        cst4[nt] = cn;
        hreg4[nt] = ov * ftanh(cn);
      }
    }
  }

  // final h -> hout
  #pragma unroll
  for (int ti=0; ti<3; ++ti){
    int j = (w*3+ti)*4 + hi;
    #pragma unroll
    for (int nt=0; nt<2; ++nt)
      hout[(n0 + nt*16 + lo)*CH + j] = hreg[ti][nt];
  }
  if (w == 7){
    #pragma unroll
    for (int nt=0; nt<2; ++nt)
      hout[(n0 + nt*16 + lo)*CH + 96 + hi] = hreg4[nt];
  }
}

// ---------------- xbf = [word_emb gather | hf+hb | 0-pad], bf16 [8192][416]
__global__ void k_build_x(const int* __restrict__ sent, const float* __restrict__ wemb,
                          const float* __restrict__ hf, const float* __restrict__ hb,
                          ushort_t* __restrict__ xbf){
  long i = (long)blockIdx.x*256 + threadIdx.x;
  if (i >= (long)BS*XDP) return;
  int n = (int)(i / XDP), e = (int)(i - (long)n*XDP);
  float v = 0.f;
  if (e < EMBD) v = wemb[(long)sent[n]*EMBD + e];
  else if (e < XD) { int jj = e-EMBD; v = hf[n*CH+jj] + hb[n*CH+jj]; }
  xbf[i] = f2bf(v);
}

// ---------------- Wi f32 -> bf16 padded: wiP[dir][1024][416]
__global__ void k_cvt_wi(const float* __restrict__ wiF, const float* __restrict__ wiB,
                         ushort_t* __restrict__ wiP){
  int i = blockIdx.x*256 + threadIdx.x;
  if (i >= 2*WG*XDP) return;
  int dir = i >= WG*XDP;
  int ii = dir ? i - WG*XDP : i;
  int n = ii / XDP, k = ii - n*XDP;
  const float* src = dir ? wiB : wiF;
  wiP[i] = (k < XD) ? f2bf(src[n*XD + k]) : (ushort_t)0;
}

// ---------------- word input-gate GEMM via bf16 MFMA; writes P layout directly.
// P[dir][t][sb][sl][m'=j*4+g]
__global__ __launch_bounds__(256) void k_gemm_mfma(const ushort_t* __restrict__ xbf, const int* __restrict__ lengths,
    const ushort_t* __restrict__ wiP, const float* __restrict__ wbF, const float* __restrict__ wbB,
    ushort_t* __restrict__ P)
{
  const int rev = blockIdx.z;
  const int b = blockIdx.x;
  const int n0 = blockIdx.y * 128;
  const float* bias = rev ? wbB : wbF;
  const int m0 = b*Ss;
  const int L = lengths[b];

  __shared__ ushort_t As[128*32];
  __shared__ ushort_t Bs[128*32];
  __shared__ float bl[128];

  const int tid = threadIdx.x;
  const int lane = tid & 63, w = tid >> 6;
  const int lo = lane & 15, hi = lane >> 4;
  const int wm0 = (w>>1)*64, wn0 = (w&1)*64;

  if (tid < 128) bl[tid] = bias[n0 + tid];

  long abase[2], bbase[2];
  #pragma unroll
  for (int u=0; u<2; ++u){
    int cid = u*256 + tid;
    int r = cid >> 2, kc = (cid & 3)*8;
    int srow;
    if (!rev) srow = m0 + r;
    else { int rr = L-1-r; srow = m0 + (rr < 0 ? 0 : rr); }
    abase[u] = (long)srow*XDP + kc;
    bbase[u] = ((long)rev*WG + n0 + r)*XDP + kc;
  }

  f32x4 acc[4][4];
  #pragma unroll
  for (int i=0;i<4;i++)
    #pragma unroll
    for (int q=0;q<4;q++){ acc[i][q][0]=0.f; acc[i][q][1]=0.f; acc[i][q][2]=0.f; acc[i][q][3]=0.f; }

  bf16x8 avn[2], bvn[2];
  #pragma unroll
  for (int u=0; u<2; ++u){
    avn[u] = *(const bf16x8*)&xbf[abase[u]];
    bvn[u] = *(const bf16x8*)&wiP[bbase[u]];
  }

  #pragma unroll 1
  for (int kt=0; kt<13; ++kt){
    bf16x8 av[2], bv[2];
    #pragma unroll
    for (int u=0; u<2; ++u){ av[u]=avn[u]; bv[u]=bvn[u]; }
    if (kt < 12){
      int k0 = (kt+1)*32;
      #pragma unroll
      for (int u=0; u<2; ++u){
        avn[u] = *(const bf16x8*)&xbf[abase[u] + k0];
        bvn[u] = *(const bf16x8*)&wiP[bbase[u] + k0];
      }
    }
    LBAR();   // all frag reads of previous tile done
    #pragma unroll
    for (int u=0; u<2; ++u){
      *(bf16x8*)&As[(u*256 + tid)*8] = av[u];
      *(bf16x8*)&Bs[(u*256 + tid)*8] = bv[u];
    }
    LBAR();   // writes visible
    bf16x8 af[4], bfr[4];
    #pragma unroll
    for (int mt=0; mt<4; ++mt) af[mt] = *(const bf16x8*)&As[(wm0 + mt*16 + lo)*32 + hi*8];
    #pragma unroll
    for (int nt=0; nt<4; ++nt) bfr[nt] = *(const bf16x8*)&Bs[(wn0 + nt*16 + lo)*32 + hi*8];
    #pragma unroll
    for (int mt=0; mt<4; ++mt)
      #pragma unroll
      for (int nt=0; nt<4; ++nt)
        acc[mt][nt] = __builtin_amdgcn_mfma_f32_16x16x32_bf16(af[mt], bfr[nt], acc[mt][nt], 0,0,0);
  }

  LBAR();
  #pragma unroll
  for (int nt=0; nt<4; ++nt){
    int n = n0 + wn0 + nt*16 + lo;            // gate-major col = g*256 + j
    float bn = bl[wn0 + nt*16 + lo];
    int mp = (n & 255)*4 + (n >> 8);          // m' = j*4 + g
    #pragma unroll
    for (int mt=0; mt<4; ++mt){
      #pragma unroll
      for (int r=0; r<4; ++r){
        int t = wm0 + mt*16 + hi*4 + r;       // 0..127
        long pidx = ((((long)rev*Ss + t)*16 + (b>>2))*4 + (b&3))*1024 + mp;
        P[pidx] = f2bf(acc[mt][nt][r] + bn);
      }
    }
  }
}

// ---------------- word LSTM recurrence via int8 MFMA K=64; Wh resident in registers.
__global__ __launch_bounds__(512, 2) void k_word_i8(
    const signed char* __restrict__ whq, const float* __restrict__ dmg,
    const ushort_t* __restrict__ P, float* __restrict__ hfw, float* __restrict__ hrw)
{
  const int dir = blockIdx.y, sb = blockIdx.x;
  const int tid = threadIdx.x, lane = tid & 63, w = tid >> 6;
  float* hout = dir ? hrw : hfw;

  __shared__ signed char hq[2][4][320];      // stride 320 -> 2-way bank aliasing (free)
  if (tid < 320) ((int*)hq)[tid] = 0;        // zero hq[0]

  const int hi = lane >> 4;
  const int lo = lane & 15;
  const int sq = lo & 3;
  const int g2 = lo >> 2;

  int4v wfr[8][4];
  #pragma unroll
  for (int ti=0; ti<8; ++ti){
    int mA = (w*8+ti)*16 + lo;
    #pragma unroll
    for (int kf=0; kf<4; ++kf)
      wfr[ti][kf] = *(const int4v*)&whq[(dir*1024 + mA)*HID + kf*64 + hi*16];
  }
  f32x4 dmq[2];
  #pragma unroll
  for (int u=0; u<2; ++u)
    dmq[u] = *(const f32x4*)&dmg[dir*1024 + (w*8 + g2*2+u)*16 + hi*4];

  float cst[2] = {0.f, 0.f};

  const ushort_t* Pd = P + (long)dir*8388608 + (sb*4 + sq)*1024;
  const ushort_t* gp0 = Pd + (w*8 + g2*2+0)*16 + hi*4;
  const ushort_t* gp1 = Pd + (w*8 + g2*2+1)*16 + hi*4;

  short4v gA[2], gB[2], gC[2];
  gA[0] = *(const short4v*)gp0;           gA[1] = *(const short4v*)gp1;
  gB[0] = *(const short4v*)(gp0 + 65536); gB[1] = *(const short4v*)(gp1 + 65536);

  const int j0 = (w*8 + g2*2)*4 + hi;     // j for u=0; u=1 is j0+4
  const long hob = (long)(sb*4 + sq)*Ss*HID;

  int p = 0;
  __syncthreads();

  #pragma unroll 1
  for (int t=0; t<Ss; ++t){
    int t2 = (t+2 < Ss) ? (t+2) : t;
    gC[0] = *(const short4v*)(gp0 + t2*65536);
    gC[1] = *(const short4v*)(gp1 + t2*65536);

    LBAR();   // h_{t-1} writes visible; global prefetch stays in flight

    int4v bfr[4];
    #pragma unroll
    for (int kf=0; kf<4; ++kf)
      bfr[kf] = *(const int4v*)&hq[p][sq][kf*64 + hi*16];

    __builtin_amdgcn_s_setprio(1);
    int4v acc[8];
    #pragma unroll
    for (int ti=0; ti<8; ++ti){
      int4v a = {0,0,0,0};
      #pragma unroll
      for (int kf=0; kf<4; ++kf)
        a = __builtin_amdgcn_mfma_i32_16x16x64_i8(wfr[ti][kf], bfr[kf], a, 0,0,0);
      acc[ti] = a;
    }
    __builtin_amdgcn_s_setprio(0);

    #pragma unroll
    for (int u=0; u<2; ++u){
      int4v x0 = sel4(g2 & 1, acc[2+u], acc[0+u]);
      int4v x1 = sel4(g2 & 1, acc[6+u], acc[4+u]);
      int4v aS = sel4(g2 & 2, x1, x0);
      float g0v = fmaf((float)aS[0], dmq[u][0], bf2f((ushort_t)gA[u][0]));
      float g1v = fmaf((float)aS[1], dmq[u][1], bf2f((ushort_t)gA[u][1]));
      float g2v = fmaf((float)aS[2], dmq[u][2], bf2f((ushort_t)gA[u][2]));
      float g3v = fmaf((float)aS[3], dmq[u][3], bf2f((ushort_t)gA[u][3]));
      float iv = fsig(g0v), fv = fsig(g1v), gg = ftanh(g2v), ov = fsig(g3v);
      float cn = fmaf(fv, cst[u], iv*gg);
      cst[u] = cn;
      float hn = ov * ftanh(cn);
      int j = j0 + u*4;
      hout[hob + (long)t*HID + j] = hn;
      hq[1-p][sq][j] = (signed char)__float2int_rn(hn * 127.0f);
    }

    gA[0]=gB[0]; gA[1]=gB[1]; gB[0]=gC[0]; gB[1]=gC[1];
    p ^= 1;
  }
}

// ---------------- emissions: emit = concat(h_fwd, h_bwd)*valid @ We^T + be
__global__ __launch_bounds__(128) void k_emit(const float* __restrict__ hfw, const float* __restrict__ hrw,
    const int* __restrict__ lengths, const float* __restrict__ We, const float* __restrict__ be,
    float* __restrict__ emit)
{
  __shared__ float Wl[NT*516];
  const int b = blockIdx.x, tg = blockIdx.y;
  const int tid = threadIdx.x;
  for (int i = tid; i < NT*512; i += 128)
    Wl[(i>>9)*516 + (i&511)] = We[i];
  __syncthreads();
  const int L = lengths[b];
  const int j = tid & 63;
  const int th = tid >> 6;
  float bej = (j<NT) ? be[j] : 0.f;
  for (int ttq=0; ttq<8; ttq++){
    int t = tg*16 + th*8 + ttq;
    int n = b*Ss + t;
    float acc = bej;
    if (j < NT && t < L){
      const float* hf_ = hfw + (long)n*HID;
      const float* hb_ = hrw + (long)(b*Ss + (L-1-t))*HID;
      const float* wr = Wl + j*516;
      for (int k=0;k<HID;k+=4){
        float4 hv = *(const float4*)(hf_+k);
        float4 wv = *(const float4*)(wr+k);
        acc += hv.x*wv.x + hv.y*wv.y + hv.z*wv.z + hv.w*wv.w;
      }
      for (int k=0;k<HID;k+=4){
        float4 hv = *(const float4*)(hb_+k);
        float4 wv = *(const float4*)(wr+256+k);
        acc += hv.x*wv.x + hv.y*wv.y + hv.z*wv.z + hv.w*wv.w;
      }
    }
    if (j < NT) emit[(long)n*NT + j] = acc;
  }
}

// ---------------- CRF: gold score + exp-domain forward algorithm; out = pred - gold
__global__ __launch_bounds__(64) void k_crf(const float* __restrict__ emit, const int* __restrict__ tags,
    const int* __restrict__ lengths, const float* __restrict__ trans, float* __restrict__ out)
{
  const int b = blockIdx.x;
  const int tid = threadIdx.x;
  __shared__ float Tl[NT*NT];
  __shared__ float A[NT];
  __shared__ float red[64];
  for (int i=tid;i<NT*NT;i+=64) Tl[i] = trans[i];
  __syncthreads();
  const int L = lengths[b];

  float gp = 0.f;
  for (int t=tid; t<L; t+=64){
    int tg = tags[b*Ss+t];
    gp += emit[(long)(b*Ss+t)*NT + tg];
    if (t>=1) gp += Tl[tags[b*Ss+t-1]*NT + tg];
  }
  red[tid] = gp; __syncthreads();
  for (int off=32; off; off>>=1){ if (tid<off) red[tid]+=red[tid+off]; __syncthreads(); }
  float gold = red[0];

  const int j = tid;
  float Ereg[NT];
  if (j < NT){
    #pragma unroll
    for (int i=0;i<NT;i++) Ereg[i] = __expf(Tl[i*NT + j]);
  }
  float a0 = (j<NT) ? emit[(long)(b*Ss)*NT + j] : -1e30f;
  float m = a0;
  #pragma unroll
  for (int off=1; off<64; off<<=1) m = fmaxf(m, __shfl_xor(m, off));
  float logZ = m;
  if (j<NT) A[j] = __expf(a0 - m);
  __syncthreads();

  for (int t=1;t<L;t++){
    float v = 0.f;
    if (j<NT){
      #pragma unroll
      for (int i=0;i<NT;i++) v = fmaf(A[i], Ereg[i], v);
      v *= __expf(emit[(long)(b*Ss+t)*NT + j]);
    }
    float mm = (j<NT) ? v : 0.f;
    #pragma unroll
    for (int off=1; off<64; off<<=1) mm = fmaxf(mm, __shfl_xor(mm, off));
    logZ += __logf(mm);
    float vn = v / mm;
    __syncthreads();
    if (j<NT) A[j] = vn;
    __syncthreads();
  }
  float s = (j<NT) ? A[j] : 0.f;
  #pragma unroll
  for (int off=1; off<64; off<<=1) s += __shfl_xor(s, off);
  float pred = logZ + __logf(s);
  if (tid==0) out[b] = pred - gold;
}

extern "C" void kernel_launch(void* const* d_in, const int* in_sizes, int n_in,
                              void* d_out, int out_size, void* d_ws, size_t ws_size,
                              hipStream_t stream){
  const int*   sentences = (const int*)d_in[0];
  const int*   lengths   = (const int*)d_in[1];
  const int*   words     = (const int*)d_in[2];
  const int*   tags      = (const int*)d_in[3];
  const float* char_emb  = (const float*)d_in[4];
  const float* cWi_f = (const float*)d_in[5];
  const float* cWh_f = (const float*)d_in[6];
  const float* cb_f  = (const float*)d_in[7];
  const float* cWi_b = (const float*)d_in[8];
  const float* cWh_b = (const float*)d_in[9];
  const float* cb_b  = (const float*)d_in[10];
  const float* word_emb = (const float*)d_in[11];
  const float* wWi_f = (const float*)d_in[12];
  const float* wWh_f = (const float*)d_in[13];
  const float* wb_f  = (const float*)d_in[14];
  const float* wWi_b = (const float*)d_in[15];
  const float* wWh_b = (const float*)d_in[16];
  const float* wb_b  = (const float*)d_in[17];
  const float* We   = (const float*)d_in[18];
  const float* be   = (const float*)d_in[19];
  const float* trans= (const float*)d_in[20];
  float* out = (float*)d_out;

  float* ws = (float*)d_ws;
  float* hf   = ws;                               // 819200 f32
  float* hb   = hf  + 819200;                     // 819200 f32
  float* hfw  = hb  + 819200;                     // 2097152 f32
  float* hrw  = hfw + 2097152;                    // 2097152 f32
  float* emit = hrw + 2097152;                    // 409600 f32
  float* dm   = emit + 409600;                    // 2048 f32
  ushort_t* xbf = (ushort_t*)(dm + 2048);         // 8192*416 bf16
  ushort_t* wiP = xbf + 3407872;                  // 2*1024*416 bf16
  ushort_t* P   = wiP + 851968;                   // 16777216 bf16
  signed char* whq = (signed char*)(P + 16777216);// 524288 i8

  k_cvt_whq<<<dim3(512), 256, 0, stream>>>(wWh_f, wWh_b, whq, dm);
  k_cvt_wi<<<dim3(3333), 256, 0, stream>>>(wWi_f, wWi_b, wiP);
  k_char_mfma<<<dim3(256,2), 512, 0, stream>>>(words, char_emb,
      cWi_f, cWh_f, cb_f, hf,
      cWi_b, cWh_b, cb_b, hb);
  k_build_x<<<dim3(13312), 256, 0, stream>>>(sentences, word_emb, hf, hb, xbf);
  k_gemm_mfma<<<dim3(64,8,2), 256, 0, stream>>>(xbf, lengths, wiP, wb_f, wb_b, P);
  k_word_i8<<<dim3(16,2), 512, 0, stream>>>(whq, dm, P, hfw, hrw);
  k_emit<<<dim3(64,8), 128, 0, stream>>>(hfw, hrw, lengths, We, be, emit);
  k_crf<<<dim3(64), 64, 0, stream>>>(emit, tags, lengths, trans, out);
}